// Round 7
// baseline (367.694 us; speedup 1.0000x reference)
//
#include <hip/hip_runtime.h>

#define N_NODES 100000
#define N_EDGES 1600000
#define DIM 128
#define ACT 512
#define NG 64
#define SCAN_B 1024
#define SCAN_NB ((N_NODES + SCAN_B - 1) / SCAN_B)   // 98
#define ZB 500
#define CHUNK 200   // ZB*CHUNK == N_NODES
#define GRP 8

// ---------------- CSR build ----------------

__global__ void k_count(const int* __restrict__ dst, int* __restrict__ cnt,
                        int* __restrict__ epos) {
    int e = blockIdx.x * blockDim.x + threadIdx.x;
    if (e < N_EDGES) {
        int d = dst[e];
        epos[e] = atomicAdd(&cnt[d], 1);
    }
}

// scan phase 1 + dis + xd pack fused
__global__ void k_scan1(const int* __restrict__ cnt, int* __restrict__ rowptr,
                        int* __restrict__ partial, float* __restrict__ dis,
                        const float* __restrict__ x, float4* __restrict__ xd) {
    __shared__ int s[SCAN_B];
    int t = threadIdx.x;
    int idx = blockIdx.x * SCAN_B + t;
    int v = (idx < N_NODES) ? cnt[idx] : 0;
    if (idx < N_NODES) {
        float d = rsqrtf((float)(v + 1));
        dis[idx] = d;
        float4 p;
        p.x = x[idx * 3 + 0] * d;
        p.y = x[idx * 3 + 1] * d;
        p.z = x[idx * 3 + 2] * d;
        p.w = d;
        xd[idx] = p;
    }
    s[t] = v;
    __syncthreads();
    for (int off = 1; off < SCAN_B; off <<= 1) {
        int add = (t >= off) ? s[t - off] : 0;
        __syncthreads();
        s[t] += add;
        __syncthreads();
    }
    if (idx < N_NODES) rowptr[idx] = s[t] - v;
    if (t == SCAN_B - 1) partial[blockIdx.x] = s[SCAN_B - 1];
}

__global__ void k_scan2(int* __restrict__ partial, int* __restrict__ rowptr) {
    __shared__ int s[128];
    int t = threadIdx.x;
    int v = (t < SCAN_NB) ? partial[t] : 0;
    s[t] = v;
    __syncthreads();
    for (int off = 1; off < 128; off <<= 1) {
        int add = (t >= off) ? s[t - off] : 0;
        __syncthreads();
        s[t] += add;
        __syncthreads();
    }
    if (t < SCAN_NB) partial[t] = s[t] - v;
    if (t == 127) rowptr[N_NODES] = s[127];
}

__global__ void k_scan3(int* __restrict__ rowptr, const int* __restrict__ partial) {
    int idx = blockIdx.x * SCAN_B + threadIdx.x;
    if (idx < N_NODES) rowptr[idx] += partial[blockIdx.x];
}

__global__ void k_fill(const int* __restrict__ src, const int* __restrict__ dst,
                       const int* __restrict__ rowptr, const int* __restrict__ epos,
                       int* __restrict__ csr) {
    int e = blockIdx.x * blockDim.x + threadIdx.x;
    if (e < N_EDGES) {
        csr[rowptr[dst[e]] + epos[e]] = src[e];
    }
}

// ---------------- layer 1 aggregation (rank-3) ----------------

// agg[i] = dis[i] * (xd[i].xyz + sum_{s in in(i)} xd[s].xyz)
__global__ void k_agg1(const float4* __restrict__ xd, const int* __restrict__ rowptr,
                       const int* __restrict__ csr, float4* __restrict__ agg) {
    int i = blockIdx.x * blockDim.x + threadIdx.x;
    if (i >= N_NODES) return;
    int r0 = rowptr[i], r1 = rowptr[i + 1];
    float4 self = xd[i];
    float d = self.w;
    float a0 = self.x, a1 = self.y, a2 = self.z;
    int j = r0;
    for (; j + 4 <= r1; j += 4) {
        int s0 = csr[j + 0], s1 = csr[j + 1], s2 = csr[j + 2], s3 = csr[j + 3];
        float4 v0 = xd[s0];
        float4 v1 = xd[s1];
        float4 v2 = xd[s2];
        float4 v3 = xd[s3];
        a0 += (v0.x + v1.x) + (v2.x + v3.x);
        a1 += (v0.y + v1.y) + (v2.y + v3.y);
        a2 += (v0.z + v1.z) + (v2.z + v3.z);
    }
    for (; j < r1; ++j) {
        float4 v = xd[csr[j]];
        a0 += v.x;
        a1 += v.y;
        a2 += v.z;
    }
    float4 o;
    o.x = a0 * d;
    o.y = a1 * d;
    o.z = a2 * d;
    o.w = 0.f;
    agg[i] = o;
}

// ---------------- layer-2 pooled-coefficient path ----------------

// c[s][g] += dis_d*dis_s for every edge s->d with batch[d]=g; plus self dis_i^2
__global__ void k_coef(const int* __restrict__ src, const int* __restrict__ dst,
                       const int* __restrict__ batch, const float* __restrict__ dis,
                       float* __restrict__ c) {
    int e = blockIdx.x * blockDim.x + threadIdx.x;
    if (e < N_EDGES) {
        int s = src[e], d = dst[e];
        atomicAdd(&c[(size_t)s * NG + batch[d]], dis[d] * dis[s]);
    } else {
        int i = e - N_EDGES;
        if (i < N_NODES) {
            float d = dis[i];
            atomicAdd(&c[(size_t)i * NG + batch[i]], d * d);
        }
    }
}

// zpart[b][g][n] = sum_{s in chunk b} c[s][g] * relu(agg_s @ W1[:,n] + b1[n])
// u is recomputed in-register from agg (rank-3) — never materialized.
__global__ __launch_bounds__(256) void k_zgemm(const float4* __restrict__ agg,
                                               const float* __restrict__ c,
                                               const float* __restrict__ W1,
                                               const float* __restrict__ b1,
                                               float* __restrict__ zpart) {
    __shared__ float cs[GRP][NG];
    __shared__ float4 as[GRP];
    int t = threadIdx.x;
    int a = t >> 5;      // 0..7  -> owns g in {a, a+8, ..., a+56}
    int b = t & 31;      // 0..31 -> owns n in {b, b+32, b+64, b+96}
    float w1r0[4], w1r1[4], w1r2[4], b1r[4];
#pragma unroll
    for (int j = 0; j < 4; ++j) {
        int n = b + j * 32;
        w1r0[j] = W1[0 * DIM + n];
        w1r1[j] = W1[1 * DIM + n];
        w1r2[j] = W1[2 * DIM + n];
        b1r[j]  = b1[n];
    }
    float acc[8][4];
#pragma unroll
    for (int gi = 0; gi < 8; ++gi)
#pragma unroll
        for (int j = 0; j < 4; ++j) acc[gi][j] = 0.f;

    int s0 = blockIdx.x * CHUNK;
    for (int base = 0; base < CHUNK; base += GRP) {
        __syncthreads();
        {
            int nn = t >> 5;
            int col = t & 31;
            int s = s0 + base + nn;
            cs[nn][col]      = c[(size_t)s * NG + col];
            cs[nn][col + 32] = c[(size_t)s * NG + col + 32];
            if (t < GRP) as[t] = agg[s0 + base + t];
        }
        __syncthreads();
#pragma unroll
        for (int nn = 0; nn < GRP; ++nn) {
            float4 ag = as[nn];
            float u[4];
#pragma unroll
            for (int j = 0; j < 4; ++j) {
                float h = fmaf(ag.x, w1r0[j], fmaf(ag.y, w1r1[j], fmaf(ag.z, w1r2[j], b1r[j])));
                u[j] = fmaxf(h, 0.f);
            }
#pragma unroll
            for (int gi = 0; gi < 8; ++gi) {
                float cv = cs[nn][a + gi * 8];
#pragma unroll
                for (int j = 0; j < 4; ++j)
                    acc[gi][j] = fmaf(cv, u[j], acc[gi][j]);
            }
        }
    }
    float* zp = zpart + (size_t)blockIdx.x * (NG * DIM);
#pragma unroll
    for (int gi = 0; gi < 8; ++gi) {
        int g = a + gi * 8;
#pragma unroll
        for (int j = 0; j < 4; ++j) {
            int n = b + j * 32;
            zp[g * DIM + n] = acc[gi][j];
        }
    }
}

// z[i] = sum_b zpart[b][i]
__global__ void k_zred(const float* __restrict__ zpart, float* __restrict__ z) {
    int i = blockIdx.x * blockDim.x + threadIdx.x;
    if (i >= NG * DIM) return;
    float acc = 0.f;
    for (int b = 0; b < ZB; ++b) acc += zpart[(size_t)b * (NG * DIM) + i];
    z[i] = acc;
}

// ---------------- head ----------------

__global__ void k_bounds(const int* __restrict__ batch, float* __restrict__ cnts) {
    __shared__ int start[NG + 1];
    int t = threadIdx.x;
    if (t <= NG) {
        int lo = 0, hi = N_NODES;
        while (lo < hi) {
            int mid = (lo + hi) >> 1;
            if (batch[mid] < t) lo = mid + 1; else hi = mid;
        }
        start[t] = lo;
    }
    __syncthreads();
    if (t < NG) cnts[t] = (float)(start[t + 1] - start[t]);
}

// embed[g][n] = (z[g][:] @ W2[:,n]) / cnt_g + b2[n]
__global__ void k_poolmix(const float* __restrict__ z, const float* __restrict__ W2,
                          const float* __restrict__ b2, const float* __restrict__ cnts,
                          float* __restrict__ embed) {
    int id = blockIdx.x * blockDim.x + threadIdx.x;
    if (id >= NG * DIM) return;
    int g = id >> 7, n = id & 127;
    float acc = 0.f;
#pragma unroll 4
    for (int k = 0; k < DIM; ++k) acc = fmaf(z[g * DIM + k], W2[k * DIM + n], acc);
    embed[id] = acc / fmaxf(cnts[g], 1.0f) + b2[n];
}

// q[g][a] = embed[g][:] @ Wf[:,a] + bf[a]
__global__ void k_final(const float* __restrict__ embed, const float* __restrict__ Wf,
                        const float* __restrict__ bf, float* __restrict__ out) {
    int id = blockIdx.x * blockDim.x + threadIdx.x;
    if (id >= NG * ACT) return;
    int g = id >> 9, a = id & 511;
    float acc = 0.f;
#pragma unroll 4
    for (int c = 0; c < DIM; ++c) acc = fmaf(embed[g * DIM + c], Wf[c * ACT + a], acc);
    out[id] = acc + bf[a];
}

// ---------------- launch ----------------

static inline size_t align256(size_t x) { return (x + 255) & ~(size_t)255; }

extern "C" void kernel_launch(void* const* d_in, const int* in_sizes, int n_in,
                              void* d_out, int out_size, void* d_ws, size_t ws_size,
                              hipStream_t stream) {
    const float* x  = (const float*)d_in[0];
    const int*   ei = (const int*)d_in[1];
    const int*   batch = (const int*)d_in[2];
    const float* W1 = (const float*)d_in[3];
    const float* b1 = (const float*)d_in[4];
    const float* W2 = (const float*)d_in[5];
    const float* b2 = (const float*)d_in[6];
    const float* Wf = (const float*)d_in[7];
    const float* bf = (const float*)d_in[8];
    float* out = (float*)d_out;

    const int* src = ei;
    const int* dst = ei + N_EDGES;

    char* ws = (char*)d_ws;
    size_t off = 0;
    float* dis     = (float*)(ws + off); off = align256(off + N_NODES * 4);
    int*   rowptr  = (int*)(ws + off);   off = align256(off + (N_NODES + 1) * 4);
    int*   cnt     = (int*)(ws + off);   off = align256(off + N_NODES * 4);
    int*   partial = (int*)(ws + off);   off = align256(off + SCAN_NB * 4);
    int*   epos    = (int*)(ws + off);   off = align256(off + N_EDGES * 4);
    int*   csr     = (int*)(ws + off);   off = align256(off + N_EDGES * 4);
    float4* xd     = (float4*)(ws + off); off = align256(off + (size_t)N_NODES * 16);
    float4* agg    = (float4*)(ws + off); off = align256(off + (size_t)N_NODES * 16);
    float* c       = (float*)(ws + off); off = align256(off + (size_t)N_NODES * NG * 4);
    float* zpart   = (float*)(ws + off); off = align256(off + (size_t)ZB * NG * DIM * 4);
    float* z       = (float*)(ws + off); off = align256(off + NG * DIM * 4);
    float* embed   = (float*)(ws + off); off = align256(off + NG * DIM * 4);
    float* cnts    = (float*)(ws + off); off = align256(off + NG * 4);

    hipMemsetAsync(cnt, 0, N_NODES * 4, stream);
    hipMemsetAsync(c, 0, (size_t)N_NODES * NG * 4, stream);

    k_count<<<(N_EDGES + 255) / 256, 256, 0, stream>>>(dst, cnt, epos);
    k_scan1<<<SCAN_NB, SCAN_B, 0, stream>>>(cnt, rowptr, partial, dis, x, xd);
    k_scan2<<<1, 128, 0, stream>>>(partial, rowptr);
    k_scan3<<<SCAN_NB, SCAN_B, 0, stream>>>(rowptr, partial);
    k_fill<<<(N_EDGES + 255) / 256, 256, 0, stream>>>(src, dst, rowptr, epos, csr);

    k_coef<<<(N_EDGES + N_NODES + 255) / 256, 256, 0, stream>>>(src, dst, batch, dis, c);
    k_agg1<<<(N_NODES + 255) / 256, 256, 0, stream>>>(xd, rowptr, csr, agg);
    k_zgemm<<<ZB, 256, 0, stream>>>(agg, c, W1, b1, zpart);
    k_zred<<<(NG * DIM + 255) / 256, 256, 0, stream>>>(zpart, z);

    k_bounds<<<1, 128, 0, stream>>>(batch, cnts);
    k_poolmix<<<(NG * DIM + 255) / 256, 256, 0, stream>>>(z, W2, b2, cnts, embed);
    k_final<<<(NG * ACT + 255) / 256, 256, 0, stream>>>(embed, Wf, bf, out);
}

// Round 8
// 367.531 us; speedup vs baseline: 1.0004x; 1.0004x over previous
//
#include <hip/hip_runtime.h>

#define N_NODES 100000
#define N_EDGES 1600000
#define DIM 128
#define ACT 512
#define NG 64
#define SCAN_B 1024
#define SCAN_NB ((N_NODES + SCAN_B - 1) / SCAN_B)   // 98
#define CHUNK 128
#define NCH 2
#define ZBLK ((N_NODES + CHUNK * NCH - 1) / (CHUNK * NCH))   // 391

// ---------------- CSR build (both directions in one pass) ----------------

__global__ void k_count(const int* __restrict__ src, const int* __restrict__ dst,
                        int* __restrict__ cnt, int* __restrict__ epos,
                        int* __restrict__ cnt2, int* __restrict__ epos2) {
    int e = blockIdx.x * blockDim.x + threadIdx.x;
    if (e < N_EDGES) {
        epos[e]  = atomicAdd(&cnt[dst[e]], 1);
        epos2[e] = atomicAdd(&cnt2[src[e]], 1);
    }
}

// dual scan phase 1 + dis/xd pack
__global__ void k_scan1(const int* __restrict__ cnt, int* __restrict__ rowptr,
                        int* __restrict__ partial,
                        const int* __restrict__ cnt2, int* __restrict__ rowptr2,
                        int* __restrict__ partial2,
                        float* __restrict__ dis,
                        const float* __restrict__ x, float4* __restrict__ xd) {
    __shared__ int s[SCAN_B];
    int t = threadIdx.x;
    int idx = blockIdx.x * SCAN_B + t;
    int v = (idx < N_NODES) ? cnt[idx] : 0;
    if (idx < N_NODES) {
        float d = rsqrtf((float)(v + 1));
        dis[idx] = d;
        float4 p;
        p.x = x[idx * 3 + 0] * d;
        p.y = x[idx * 3 + 1] * d;
        p.z = x[idx * 3 + 2] * d;
        p.w = d;
        xd[idx] = p;
    }
    s[t] = v;
    __syncthreads();
    for (int off = 1; off < SCAN_B; off <<= 1) {
        int add = (t >= off) ? s[t - off] : 0;
        __syncthreads();
        s[t] += add;
        __syncthreads();
    }
    if (idx < N_NODES) rowptr[idx] = s[t] - v;
    if (t == SCAN_B - 1) partial[blockIdx.x] = s[SCAN_B - 1];
    __syncthreads();
    int v2 = (idx < N_NODES) ? cnt2[idx] : 0;
    s[t] = v2;
    __syncthreads();
    for (int off = 1; off < SCAN_B; off <<= 1) {
        int add = (t >= off) ? s[t - off] : 0;
        __syncthreads();
        s[t] += add;
        __syncthreads();
    }
    if (idx < N_NODES) rowptr2[idx] = s[t] - v2;
    if (t == SCAN_B - 1) partial2[blockIdx.x] = s[SCAN_B - 1];
}

__global__ void k_scan2(int* __restrict__ partial, int* __restrict__ rowptr,
                        int* __restrict__ partial2, int* __restrict__ rowptr2) {
    __shared__ int s[128];
    int t = threadIdx.x;
    int v = (t < SCAN_NB) ? partial[t] : 0;
    s[t] = v;
    __syncthreads();
    for (int off = 1; off < 128; off <<= 1) {
        int add = (t >= off) ? s[t - off] : 0;
        __syncthreads();
        s[t] += add;
        __syncthreads();
    }
    if (t < SCAN_NB) partial[t] = s[t] - v;
    if (t == 127) rowptr[N_NODES] = s[127];
    __syncthreads();
    int v2 = (t < SCAN_NB) ? partial2[t] : 0;
    s[t] = v2;
    __syncthreads();
    for (int off = 1; off < 128; off <<= 1) {
        int add = (t >= off) ? s[t - off] : 0;
        __syncthreads();
        s[t] += add;
        __syncthreads();
    }
    if (t < SCAN_NB) partial2[t] = s[t] - v2;
    if (t == 127) rowptr2[N_NODES] = s[127];
}

__global__ void k_scan3(int* __restrict__ rowptr, const int* __restrict__ partial,
                        int* __restrict__ rowptr2, const int* __restrict__ partial2) {
    int idx = blockIdx.x * SCAN_B + threadIdx.x;
    if (idx < N_NODES) {
        rowptr[idx] += partial[blockIdx.x];
        rowptr2[idx] += partial2[blockIdx.x];
    }
}

// both fills in one edge pass
__global__ void k_fill(const int* __restrict__ src, const int* __restrict__ dst,
                       const int* __restrict__ rowptr, const int* __restrict__ epos,
                       int* __restrict__ csr,
                       const int* __restrict__ rowptr2, const int* __restrict__ epos2,
                       int* __restrict__ csr2) {
    int e = blockIdx.x * blockDim.x + threadIdx.x;
    if (e < N_EDGES) {
        int s = src[e], d = dst[e];
        csr[rowptr[d] + epos[e]] = s;
        csr2[rowptr2[s] + epos2[e]] = d;
    }
}

// ---------------- layer 1 aggregation (rank-3) ----------------

__global__ void k_agg1(const float4* __restrict__ xd, const int* __restrict__ rowptr,
                       const int* __restrict__ csr, float4* __restrict__ agg) {
    int i = blockIdx.x * blockDim.x + threadIdx.x;
    if (i >= N_NODES) return;
    int r0 = rowptr[i], r1 = rowptr[i + 1];
    float4 self = xd[i];
    float d = self.w;
    float a0 = self.x, a1 = self.y, a2 = self.z;
    int j = r0;
    for (; j + 4 <= r1; j += 4) {
        int s0 = csr[j + 0], s1 = csr[j + 1], s2 = csr[j + 2], s3 = csr[j + 3];
        float4 v0 = xd[s0];
        float4 v1 = xd[s1];
        float4 v2 = xd[s2];
        float4 v3 = xd[s3];
        a0 += (v0.x + v1.x) + (v2.x + v3.x);
        a1 += (v0.y + v1.y) + (v2.y + v3.y);
        a2 += (v0.z + v1.z) + (v2.z + v3.z);
    }
    for (; j < r1; ++j) {
        float4 v = xd[csr[j]];
        a0 += v.x;
        a1 += v.y;
        a2 += v.z;
    }
    float4 o;
    o.x = a0 * d;
    o.y = a1 * d;
    o.z = a2 * d;
    o.w = 0.f;
    agg[i] = o;
}

// ---------------- fused coefficient build + z contraction ----------------
// zpart[blk][g][n] = sum_{s in blk's chunks} c[s][g] * relu(agg_s @ W1[:,n] + b1[n])
// c[s][g] built in LDS from out-CSR: c[s][g] = dis_s*sum_{d in out(s), batch[d]=g} dis_d
//                                            + [batch_s=g]*dis_s^2
__global__ __launch_bounds__(256) void k_zgemm(const float4* __restrict__ agg,
                                               const int* __restrict__ rowptr2,
                                               const int* __restrict__ csr2,
                                               const int* __restrict__ batch,
                                               const float* __restrict__ dis,
                                               const float* __restrict__ W1,
                                               const float* __restrict__ b1,
                                               float* __restrict__ zpart) {
    __shared__ float ctile[CHUNK][NG];   // 32 KB
    __shared__ int rp[CHUNK + 1];
    __shared__ float dsl[CHUNK];
    __shared__ float4 ags[CHUNK];
    int t = threadIdx.x;
    int a = t >> 5;      // 0..7 -> owns groups 8a..8a+7
    int b = t & 31;      // 0..31 -> owns n in {b, b+32, b+64, b+96}

    float w1r0[4], w1r1[4], w1r2[4], b1r[4];
#pragma unroll
    for (int j = 0; j < 4; ++j) {
        int n = b + j * 32;
        w1r0[j] = W1[0 * DIM + n];
        w1r1[j] = W1[1 * DIM + n];
        w1r2[j] = W1[2 * DIM + n];
        b1r[j]  = b1[n];
    }
    float acc[8][4];
#pragma unroll
    for (int gi = 0; gi < 8; ++gi)
#pragma unroll
        for (int j = 0; j < 4; ++j) acc[gi][j] = 0.f;

    for (int ch = 0; ch < NCH; ++ch) {
        int s0 = (blockIdx.x * NCH + ch) * CHUNK;
        __syncthreads();   // protect LDS reuse across chunk iterations
        for (int idx = t; idx < CHUNK * NG; idx += 256) ((float*)ctile)[idx] = 0.f;
        for (int idx = t; idx <= CHUNK; idx += 256) {
            int s = s0 + idx;
            rp[idx] = rowptr2[s < N_NODES ? s : N_NODES];
        }
        if (t < CHUNK) {
            int s = s0 + t;
            if (s < N_NODES) {
                dsl[t] = dis[s];
                ags[t] = agg[s];
            } else {
                dsl[t] = 0.f;
                ags[t] = (float4){0.f, 0.f, 0.f, 0.f};
            }
        }
        __syncthreads();
        // edge phase: LDS atomic accumulation of coefficients
        int e0 = rp[0], e1 = rp[CHUNK];
        for (int idx = e0 + t; idx < e1; idx += 256) {
            int d = csr2[idx];
            int lo = 0, hi = CHUNK;
            while (hi - lo > 1) {
                int mid = (lo + hi) >> 1;
                if (rp[mid] <= idx) lo = mid; else hi = mid;
            }
            atomicAdd(&ctile[lo][batch[d]], dsl[lo] * dis[d]);
        }
        // self terms
        if (t < CHUNK) {
            int s = s0 + t;
            if (s < N_NODES) atomicAdd(&ctile[t][batch[s]], dsl[t] * dsl[t]);
        }
        __syncthreads();
        // compute phase
        for (int nn = 0; nn < CHUNK; ++nn) {
            float4 ag = ags[nn];
            float u[4];
#pragma unroll
            for (int j = 0; j < 4; ++j) {
                float h = fmaf(ag.x, w1r0[j], fmaf(ag.y, w1r1[j], fmaf(ag.z, w1r2[j], b1r[j])));
                u[j] = fmaxf(h, 0.f);
            }
            const float4* cr = (const float4*)&ctile[nn][a * 8];
            float4 c0 = cr[0];
            float4 c1 = cr[1];
            float cv[8] = {c0.x, c0.y, c0.z, c0.w, c1.x, c1.y, c1.z, c1.w};
#pragma unroll
            for (int gi = 0; gi < 8; ++gi) {
#pragma unroll
                for (int j = 0; j < 4; ++j)
                    acc[gi][j] = fmaf(cv[gi], u[j], acc[gi][j]);
            }
        }
    }
    float* zp = zpart + (size_t)blockIdx.x * (NG * DIM);
#pragma unroll
    for (int gi = 0; gi < 8; ++gi) {
        int g = a * 8 + gi;
#pragma unroll
        for (int j = 0; j < 4; ++j) {
            int n = b + j * 32;
            zp[g * DIM + n] = acc[gi][j];
        }
    }
}

// z[i] = sum_b zpart[b][i]
__global__ void k_zred(const float* __restrict__ zpart, float* __restrict__ z) {
    int i = blockIdx.x * blockDim.x + threadIdx.x;
    if (i >= NG * DIM) return;
    float acc = 0.f;
    for (int b = 0; b < ZBLK; ++b) acc += zpart[(size_t)b * (NG * DIM) + i];
    z[i] = acc;
}

// ---------------- head ----------------

__global__ void k_bounds(const int* __restrict__ batch, float* __restrict__ cnts) {
    __shared__ int start[NG + 1];
    int t = threadIdx.x;
    if (t <= NG) {
        int lo = 0, hi = N_NODES;
        while (lo < hi) {
            int mid = (lo + hi) >> 1;
            if (batch[mid] < t) lo = mid + 1; else hi = mid;
        }
        start[t] = lo;
    }
    __syncthreads();
    if (t < NG) cnts[t] = (float)(start[t + 1] - start[t]);
}

// embed[g][n] = (z[g][:] @ W2[:,n]) / cnt_g + b2[n]
__global__ void k_poolmix(const float* __restrict__ z, const float* __restrict__ W2,
                          const float* __restrict__ b2, const float* __restrict__ cnts,
                          float* __restrict__ embed) {
    int id = blockIdx.x * blockDim.x + threadIdx.x;
    if (id >= NG * DIM) return;
    int g = id >> 7, n = id & 127;
    float acc = 0.f;
#pragma unroll 4
    for (int k = 0; k < DIM; ++k) acc = fmaf(z[g * DIM + k], W2[k * DIM + n], acc);
    embed[id] = acc / fmaxf(cnts[g], 1.0f) + b2[n];
}

// q[g][a] = embed[g][:] @ Wf[:,a] + bf[a]
__global__ void k_final(const float* __restrict__ embed, const float* __restrict__ Wf,
                        const float* __restrict__ bf, float* __restrict__ out) {
    int id = blockIdx.x * blockDim.x + threadIdx.x;
    if (id >= NG * ACT) return;
    int g = id >> 9, a = id & 511;
    float acc = 0.f;
#pragma unroll 4
    for (int c = 0; c < DIM; ++c) acc = fmaf(embed[g * DIM + c], Wf[c * ACT + a], acc);
    out[id] = acc + bf[a];
}

// ---------------- launch ----------------

static inline size_t align256(size_t x) { return (x + 255) & ~(size_t)255; }

extern "C" void kernel_launch(void* const* d_in, const int* in_sizes, int n_in,
                              void* d_out, int out_size, void* d_ws, size_t ws_size,
                              hipStream_t stream) {
    const float* x  = (const float*)d_in[0];
    const int*   ei = (const int*)d_in[1];
    const int*   batch = (const int*)d_in[2];
    const float* W1 = (const float*)d_in[3];
    const float* b1 = (const float*)d_in[4];
    const float* W2 = (const float*)d_in[5];
    const float* b2 = (const float*)d_in[6];
    const float* Wf = (const float*)d_in[7];
    const float* bf = (const float*)d_in[8];
    float* out = (float*)d_out;

    const int* src = ei;
    const int* dst = ei + N_EDGES;

    char* ws = (char*)d_ws;
    size_t off = 0;
    float* dis      = (float*)(ws + off); off = align256(off + N_NODES * 4);
    int*   rowptr   = (int*)(ws + off);   off = align256(off + (N_NODES + 1) * 4);
    int*   rowptr2  = (int*)(ws + off);   off = align256(off + (N_NODES + 1) * 4);
    int*   cnt      = (int*)(ws + off);   off = align256(off + N_NODES * 4);
    int*   cnt2     = (int*)(ws + off);   off = align256(off + N_NODES * 4);
    int*   partial  = (int*)(ws + off);   off = align256(off + SCAN_NB * 4);
    int*   partial2 = (int*)(ws + off);   off = align256(off + SCAN_NB * 4);
    int*   epos     = (int*)(ws + off);   off = align256(off + N_EDGES * 4);
    int*   epos2    = (int*)(ws + off);   off = align256(off + N_EDGES * 4);
    int*   csr      = (int*)(ws + off);   off = align256(off + N_EDGES * 4);
    int*   csr2     = (int*)(ws + off);   off = align256(off + N_EDGES * 4);
    float4* xd      = (float4*)(ws + off); off = align256(off + (size_t)N_NODES * 16);
    float4* agg     = (float4*)(ws + off); off = align256(off + (size_t)N_NODES * 16);
    float* zpart    = (float*)(ws + off); off = align256(off + (size_t)ZBLK * NG * DIM * 4);
    float* z        = (float*)(ws + off); off = align256(off + NG * DIM * 4);
    float* embed    = (float*)(ws + off); off = align256(off + NG * DIM * 4);
    float* cnts     = (float*)(ws + off); off = align256(off + NG * 4);

    hipMemsetAsync(cnt, 0, N_NODES * 4, stream);
    hipMemsetAsync(cnt2, 0, N_NODES * 4, stream);

    k_count<<<(N_EDGES + 255) / 256, 256, 0, stream>>>(src, dst, cnt, epos, cnt2, epos2);
    k_scan1<<<SCAN_NB, SCAN_B, 0, stream>>>(cnt, rowptr, partial, cnt2, rowptr2, partial2, dis, x, xd);
    k_scan2<<<1, 128, 0, stream>>>(partial, rowptr, partial2, rowptr2);
    k_scan3<<<SCAN_NB, SCAN_B, 0, stream>>>(rowptr, partial, rowptr2, partial2);
    k_fill<<<(N_EDGES + 255) / 256, 256, 0, stream>>>(src, dst, rowptr, epos, csr, rowptr2, epos2, csr2);

    k_agg1<<<(N_NODES + 255) / 256, 256, 0, stream>>>(xd, rowptr, csr, agg);
    k_zgemm<<<ZBLK, 256, 0, stream>>>(agg, rowptr2, csr2, batch, dis, W1, b1, zpart);
    k_zred<<<(NG * DIM + 255) / 256, 256, 0, stream>>>(zpart, z);

    k_bounds<<<1, 128, 0, stream>>>(batch, cnts);
    k_poolmix<<<(NG * DIM + 255) / 256, 256, 0, stream>>>(z, W2, b2, cnts, embed);
    k_final<<<(NG * ACT + 255) / 256, 256, 0, stream>>>(embed, Wf, bf, out);
}

// Round 9
// 271.668 us; speedup vs baseline: 1.3535x; 1.3529x over previous
//
#include <hip/hip_runtime.h>

#define N_NODES 100000
#define N_EDGES 1600000
#define DIM 128
#define ACT 512
#define NG 64
#define CHUNK 128
#define NBUK 782            // ceil(N_NODES/CHUNK)
#define NBUK2 (2 * NBUK)
#define EB 4096             // edges per partition block
#define NBLK_E 391          // ceil(N_EDGES/EB)
#define NCH 2
#define ZBLK 391            // ceil(NBUK/NCH)

// ---------------- chunk-granular edge partition (atomic-free global) ----------------

// per-block LDS histogram of dst-chunk and src-chunk -> hist[block][0..1563]
__global__ __launch_bounds__(256) void k_histA(const int* __restrict__ src,
                                               const int* __restrict__ dst,
                                               int* __restrict__ hist) {
    __shared__ int lh[NBUK2];
    int t = threadIdx.x;
    for (int i = t; i < NBUK2; i += 256) lh[i] = 0;
    __syncthreads();
    int e0 = blockIdx.x * EB;
    int e1 = min(e0 + EB, N_EDGES);
    for (int i = e0 + t; i < e1; i += 256) {
        atomicAdd(&lh[dst[i] >> 7], 1);
        atomicAdd(&lh[NBUK + (src[i] >> 7)], 1);
    }
    __syncthreads();
    int* row = hist + (size_t)blockIdx.x * NBUK2;
    for (int i = t; i < NBUK2; i += 256) row[i] = lh[i];
}

// per-bucket column scan: hist[k][b] -> exclusive prefix (in place), colsum[b]
__global__ __launch_bounds__(512) void k_bscanA(int* __restrict__ hist,
                                                int* __restrict__ colsum) {
    __shared__ int s[512];
    int b = blockIdx.x, t = threadIdx.x;
    int v = (t < NBLK_E) ? hist[(size_t)t * NBUK2 + b] : 0;
    s[t] = v;
    __syncthreads();
    for (int off = 1; off < 512; off <<= 1) {
        int add = (t >= off) ? s[t - off] : 0;
        __syncthreads();
        s[t] += add;
        __syncthreads();
    }
    if (t < NBLK_E) hist[(size_t)t * NBUK2 + b] = s[t] - v;
    if (t == 511) colsum[b] = s[511];
}

// scan bucket totals -> off_d[0..782], off_s[0..782]
__global__ __launch_bounds__(1024) void k_bscanB(const int* __restrict__ colsum,
                                                 int* __restrict__ off_d,
                                                 int* __restrict__ off_s) {
    __shared__ int s[1024];
    int t = threadIdx.x;
    int v = (t < NBUK) ? colsum[t] : 0;
    s[t] = v;
    __syncthreads();
    for (int off = 1; off < 1024; off <<= 1) {
        int add = (t >= off) ? s[t - off] : 0;
        __syncthreads();
        s[t] += add;
        __syncthreads();
    }
    if (t < NBUK) off_d[t] = s[t] - v;
    if (t == 1023) off_d[NBUK] = s[1023];
    __syncthreads();
    int v2 = (t < NBUK) ? colsum[NBUK + t] : 0;
    s[t] = v2;
    __syncthreads();
    for (int off = 1; off < 1024; off <<= 1) {
        int add = (t >= off) ? s[t - off] : 0;
        __syncthreads();
        s[t] += add;
        __syncthreads();
    }
    if (t < NBUK) off_s[t] = s[t] - v2;
    if (t == 1023) off_s[NBUK] = s[1023];
}

// hist[k][b] += bucket offset  -> global base per (block,bucket)
__global__ void k_bscanC(int* __restrict__ hist, const int* __restrict__ off_d,
                         const int* __restrict__ off_s) {
    int id = blockIdx.x * blockDim.x + threadIdx.x;
    if (id >= NBLK_E * NBUK2) return;
    int b = id % NBUK2;
    hist[id] += (b < NBUK) ? off_d[b] : off_s[b - NBUK];
}

// partition fill: payload (local7<<17)|other17, slots via LDS cursors
__global__ __launch_bounds__(256) void k_bfill(const int* __restrict__ src,
                                               const int* __restrict__ dst,
                                               const int* __restrict__ hist,
                                               int* __restrict__ edata_d,
                                               int* __restrict__ edata_s) {
    __shared__ int cur[NBUK2];
    int t = threadIdx.x;
    const int* row = hist + (size_t)blockIdx.x * NBUK2;
    for (int i = t; i < NBUK2; i += 256) cur[i] = row[i];
    __syncthreads();
    int e0 = blockIdx.x * EB;
    int e1 = min(e0 + EB, N_EDGES);
    for (int i = e0 + t; i < e1; i += 256) {
        int s = src[i], d = dst[i];
        int pd = atomicAdd(&cur[d >> 7], 1);
        edata_d[pd] = ((d & 127) << 17) | s;
        int ps = atomicAdd(&cur[NBUK + (s >> 7)], 1);
        edata_s[ps] = ((s & 127) << 17) | d;
    }
}

// ---------------- per-chunk in-degree -> dis, xd ----------------

__global__ __launch_bounds__(256) void k_indeg(const int* __restrict__ edata_d,
                                               const int* __restrict__ off_d,
                                               const float* __restrict__ x,
                                               float* __restrict__ dis,
                                               float4* __restrict__ xd) {
    __shared__ int cnt[CHUNK];
    int t = threadIdx.x;
    int b = blockIdx.x;
    if (t < CHUNK) cnt[t] = 0;
    __syncthreads();
    int e0 = off_d[b], e1 = off_d[b + 1];
    for (int i = e0 + t; i < e1; i += 256) atomicAdd(&cnt[edata_d[i] >> 17], 1);
    __syncthreads();
    if (t < CHUNK) {
        int node = b * CHUNK + t;
        if (node < N_NODES) {
            float d = rsqrtf((float)(cnt[t] + 1));
            dis[node] = d;
            float4 p;
            p.x = x[node * 3 + 0] * d;
            p.y = x[node * 3 + 1] * d;
            p.z = x[node * 3 + 2] * d;
            p.w = d;
            xd[node] = p;
        }
    }
}

// ---------------- layer-1 aggregation per dst chunk (LDS accumulate) ----------------

__global__ __launch_bounds__(256) void k_agg(const int* __restrict__ edata_d,
                                             const int* __restrict__ off_d,
                                             const float4* __restrict__ xd,
                                             float4* __restrict__ agg) {
    __shared__ float ax[CHUNK], ay[CHUNK], az[CHUNK];
    int t = threadIdx.x;
    int b = blockIdx.x;
    if (t < CHUNK) { ax[t] = 0.f; ay[t] = 0.f; az[t] = 0.f; }
    __syncthreads();
    int e0 = off_d[b], e1 = off_d[b + 1];
    for (int i = e0 + t; i < e1; i += 256) {
        int p = edata_d[i];
        int dl = p >> 17;
        int s = p & 0x1FFFF;
        float4 y = xd[s];
        atomicAdd(&ax[dl], y.x);
        atomicAdd(&ay[dl], y.y);
        atomicAdd(&az[dl], y.z);
    }
    __syncthreads();
    if (t < CHUNK) {
        int node = b * CHUNK + t;
        if (node < N_NODES) {
            float4 self = xd[node];
            float d = self.w;
            float4 o;
            o.x = (ax[t] + self.x) * d;
            o.y = (ay[t] + self.y) * d;
            o.z = (az[t] + self.z) * d;
            o.w = 0.f;
            agg[node] = o;
        }
    }
}

// ---------------- fused coefficient build + z contraction ----------------
// zpart[blk][g][n] = sum_{s in blk's chunks} c[s][g] * relu(agg_s @ W1[:,n] + b1[n])
__global__ __launch_bounds__(256) void k_zgemm(const float4* __restrict__ agg,
                                               const int* __restrict__ edata_s,
                                               const int* __restrict__ off_s,
                                               const int* __restrict__ batch,
                                               const float* __restrict__ dis,
                                               const float* __restrict__ W1,
                                               const float* __restrict__ b1,
                                               float* __restrict__ zpart) {
    __shared__ float ctile[CHUNK][NG];   // 32 KB
    __shared__ float dsl[CHUNK];
    __shared__ float4 ags[CHUNK];
    int t = threadIdx.x;
    int a = t >> 5;      // 0..7 -> owns groups 8a..8a+7
    int b = t & 31;      // 0..31 -> owns n in {b, b+32, b+64, b+96}

    float w1r0[4], w1r1[4], w1r2[4], b1r[4];
#pragma unroll
    for (int j = 0; j < 4; ++j) {
        int n = b + j * 32;
        w1r0[j] = W1[0 * DIM + n];
        w1r1[j] = W1[1 * DIM + n];
        w1r2[j] = W1[2 * DIM + n];
        b1r[j]  = b1[n];
    }
    float acc[8][4];
#pragma unroll
    for (int gi = 0; gi < 8; ++gi)
#pragma unroll
        for (int j = 0; j < 4; ++j) acc[gi][j] = 0.f;

    for (int ch = 0; ch < NCH; ++ch) {
        int chunk = blockIdx.x * NCH + ch;
        if (chunk >= NBUK) break;
        int s0 = chunk * CHUNK;
        __syncthreads();
        for (int idx = t; idx < CHUNK * NG; idx += 256) ((float*)ctile)[idx] = 0.f;
        if (t < CHUNK) {
            int s = s0 + t;
            if (s < N_NODES) {
                dsl[t] = dis[s];
                ags[t] = agg[s];
            } else {
                dsl[t] = 0.f;
                ags[t] = (float4){0.f, 0.f, 0.f, 0.f};
            }
        }
        __syncthreads();
        // edge phase: LDS accumulation of coefficients
        int e0 = off_s[chunk], e1 = off_s[chunk + 1];
        for (int i = e0 + t; i < e1; i += 256) {
            int p = edata_s[i];
            int sl = p >> 17;
            int d = p & 0x1FFFF;
            atomicAdd(&ctile[sl][batch[d]], dsl[sl] * dis[d]);
        }
        if (t < CHUNK) {
            int s = s0 + t;
            if (s < N_NODES) atomicAdd(&ctile[t][batch[s]], dsl[t] * dsl[t]);
        }
        __syncthreads();
        // compute phase
        for (int nn = 0; nn < CHUNK; ++nn) {
            float4 ag = ags[nn];
            float u[4];
#pragma unroll
            for (int j = 0; j < 4; ++j) {
                float h = fmaf(ag.x, w1r0[j], fmaf(ag.y, w1r1[j], fmaf(ag.z, w1r2[j], b1r[j])));
                u[j] = fmaxf(h, 0.f);
            }
            const float4* cr = (const float4*)&ctile[nn][a * 8];
            float4 c0 = cr[0];
            float4 c1 = cr[1];
            float cv[8] = {c0.x, c0.y, c0.z, c0.w, c1.x, c1.y, c1.z, c1.w};
#pragma unroll
            for (int gi = 0; gi < 8; ++gi) {
#pragma unroll
                for (int j = 0; j < 4; ++j)
                    acc[gi][j] = fmaf(cv[gi], u[j], acc[gi][j]);
            }
        }
    }
    float* zp = zpart + (size_t)blockIdx.x * (NG * DIM);
#pragma unroll
    for (int gi = 0; gi < 8; ++gi) {
        int g = a * 8 + gi;
#pragma unroll
        for (int j = 0; j < 4; ++j) {
            int n = b + j * 32;
            zp[g * DIM + n] = acc[gi][j];
        }
    }
}

// z[i] = sum_b zpart[b][i]
__global__ void k_zred(const float* __restrict__ zpart, float* __restrict__ z) {
    int i = blockIdx.x * blockDim.x + threadIdx.x;
    if (i >= NG * DIM) return;
    float acc = 0.f;
    for (int b = 0; b < ZBLK; ++b) acc += zpart[(size_t)b * (NG * DIM) + i];
    z[i] = acc;
}

// ---------------- head ----------------

__global__ void k_bounds(const int* __restrict__ batch, float* __restrict__ cnts) {
    __shared__ int start[NG + 1];
    int t = threadIdx.x;
    if (t <= NG) {
        int lo = 0, hi = N_NODES;
        while (lo < hi) {
            int mid = (lo + hi) >> 1;
            if (batch[mid] < t) lo = mid + 1; else hi = mid;
        }
        start[t] = lo;
    }
    __syncthreads();
    if (t < NG) cnts[t] = (float)(start[t + 1] - start[t]);
}

__global__ void k_poolmix(const float* __restrict__ z, const float* __restrict__ W2,
                          const float* __restrict__ b2, const float* __restrict__ cnts,
                          float* __restrict__ embed) {
    int id = blockIdx.x * blockDim.x + threadIdx.x;
    if (id >= NG * DIM) return;
    int g = id >> 7, n = id & 127;
    float acc = 0.f;
#pragma unroll 4
    for (int k = 0; k < DIM; ++k) acc = fmaf(z[g * DIM + k], W2[k * DIM + n], acc);
    embed[id] = acc / fmaxf(cnts[g], 1.0f) + b2[n];
}

__global__ void k_final(const float* __restrict__ embed, const float* __restrict__ Wf,
                        const float* __restrict__ bf, float* __restrict__ out) {
    int id = blockIdx.x * blockDim.x + threadIdx.x;
    if (id >= NG * ACT) return;
    int g = id >> 9, a = id & 511;
    float acc = 0.f;
#pragma unroll 4
    for (int c = 0; c < DIM; ++c) acc = fmaf(embed[g * DIM + c], Wf[c * ACT + a], acc);
    out[id] = acc + bf[a];
}

// ---------------- launch ----------------

static inline size_t align256(size_t x) { return (x + 255) & ~(size_t)255; }

extern "C" void kernel_launch(void* const* d_in, const int* in_sizes, int n_in,
                              void* d_out, int out_size, void* d_ws, size_t ws_size,
                              hipStream_t stream) {
    const float* x  = (const float*)d_in[0];
    const int*   ei = (const int*)d_in[1];
    const int*   batch = (const int*)d_in[2];
    const float* W1 = (const float*)d_in[3];
    const float* b1 = (const float*)d_in[4];
    const float* W2 = (const float*)d_in[5];
    const float* b2 = (const float*)d_in[6];
    const float* Wf = (const float*)d_in[7];
    const float* bf = (const float*)d_in[8];
    float* out = (float*)d_out;

    const int* src = ei;
    const int* dst = ei + N_EDGES;

    char* ws = (char*)d_ws;
    size_t off = 0;
    int*   hist    = (int*)(ws + off);   off = align256(off + (size_t)NBLK_E * NBUK2 * 4);
    int*   colsum  = (int*)(ws + off);   off = align256(off + NBUK2 * 4);
    int*   off_d   = (int*)(ws + off);   off = align256(off + (NBUK + 1) * 4);
    int*   off_s   = (int*)(ws + off);   off = align256(off + (NBUK + 1) * 4);
    int*   edata_d = (int*)(ws + off);   off = align256(off + (size_t)N_EDGES * 4);
    int*   edata_s = (int*)(ws + off);   off = align256(off + (size_t)N_EDGES * 4);
    float* dis     = (float*)(ws + off); off = align256(off + N_NODES * 4);
    float4* xd     = (float4*)(ws + off); off = align256(off + (size_t)N_NODES * 16);
    float4* agg    = (float4*)(ws + off); off = align256(off + (size_t)N_NODES * 16);
    float* zpart   = (float*)(ws + off); off = align256(off + (size_t)ZBLK * NG * DIM * 4);
    float* z       = (float*)(ws + off); off = align256(off + NG * DIM * 4);
    float* embed   = (float*)(ws + off); off = align256(off + NG * DIM * 4);
    float* cnts    = (float*)(ws + off); off = align256(off + NG * 4);

    k_histA<<<NBLK_E, 256, 0, stream>>>(src, dst, hist);
    k_bscanA<<<NBUK2, 512, 0, stream>>>(hist, colsum);
    k_bscanB<<<1, 1024, 0, stream>>>(colsum, off_d, off_s);
    k_bscanC<<<(NBLK_E * NBUK2 + 255) / 256, 256, 0, stream>>>(hist, off_d, off_s);
    k_bfill<<<NBLK_E, 256, 0, stream>>>(src, dst, hist, edata_d, edata_s);

    k_indeg<<<NBUK, 256, 0, stream>>>(edata_d, off_d, x, dis, xd);
    k_agg<<<NBUK, 256, 0, stream>>>(edata_d, off_d, xd, agg);
    k_zgemm<<<ZBLK, 256, 0, stream>>>(agg, edata_s, off_s, batch, dis, W1, b1, zpart);
    k_zred<<<(NG * DIM + 255) / 256, 256, 0, stream>>>(zpart, z);

    k_bounds<<<1, 128, 0, stream>>>(batch, cnts);
    k_poolmix<<<(NG * DIM + 255) / 256, 256, 0, stream>>>(z, W2, b2, cnts, embed);
    k_final<<<(NG * ACT + 255) / 256, 256, 0, stream>>>(embed, Wf, bf, out);
}